// Round 19
// baseline (192.593 us; speedup 1.0000x reference)
//
#include <hip/hip_runtime.h>

#define NN 4096
#define FIN 256
#define CC 256
#define NH 8
#define NW32 (NN / 32)  // u32 words per adj row

typedef __attribute__((ext_vector_type(8))) short short8;
typedef __attribute__((ext_vector_type(4))) float f32x4;
typedef __attribute__((ext_vector_type(4))) unsigned int u32x4;

__device__ __forceinline__ unsigned cvtpk_bf16(float lo, float hi) {
  unsigned r;
  asm("v_cvt_pk_bf16_f32 %0, %1, %2" : "=v"(r) : "v"(lo), "v"(hi));
  return r;
}

__device__ __forceinline__ unsigned short bf16rn(float x) {
  unsigned int u = __builtin_bit_cast(unsigned int, x);
  u += 0x7fffu + ((u >> 16) & 1u);
  return (unsigned short)(u >> 16);
}

__device__ __forceinline__ void gl_lds16(const void* g, void* l) {
  __builtin_amdgcn_global_load_lds(
      (const __attribute__((address_space(1))) void*)g,
      (__attribute__((address_space(3))) void*)l, 16, 0, 0);
}

// ---------------- K1: fused {GEMM+epilogue | adj bitpack} by block range ---
// blocks [0,512): GEMM g=h@W -> swizzled gTs + spack + dtc.
// blocks [512, 512+2048): bitpack (one u32 word per thread, 8x int4 stream).
// adjb[i][w] bit e = adj[i][w*32+e]!=0.
// gTs: chunk-major SWIZZLED bf16 (16B unit at [jc][c][p], p = q ^ ((c>>1)&3)).
// spack[h][n] = (e^s_src, e^{0.2 s_src}, 0, 0).
// dtc[h][jc][plane][32] = (e^sd, e^{0.2 sd}).
#define GROWS 8
#define GEMM_BLKS (NN / GROWS)                  // 512
#define BP_BLKS (NN * NW32 / 256)               // 2048
__global__ __launch_bounds__(256) void k_gemm(
    const float* __restrict__ h, const float* __restrict__ W,
    const float* __restrict__ a, const int* __restrict__ adj,
    unsigned int* __restrict__ adjb, unsigned short* __restrict__ gTs,
    float4* __restrict__ spack, float* __restrict__ dtc) {
  __shared__ float hs[GROWS][FIN];
  const int t = threadIdx.x;
  const int bx = blockIdx.x;

  if (bx >= GEMM_BLKS) {
    const int wid = (bx - GEMM_BLKS) * 256 + t;  // word index
    const int row = wid >> 7, wd = wid & 127;
    const int* src = adj + (size_t)row * NN + wd * 32;
    int4 v[8];
#pragma unroll
    for (int s = 0; s < 8; ++s) v[s] = *(const int4*)&src[s * 4];
    unsigned int bits = 0;
#pragma unroll
    for (int s = 0; s < 8; ++s) {
      bits |= (v[s].x ? 1u : 0u) << (s * 4 + 0);
      bits |= (v[s].y ? 1u : 0u) << (s * 4 + 1);
      bits |= (v[s].z ? 1u : 0u) << (s * 4 + 2);
      bits |= (v[s].w ? 1u : 0u) << (s * 4 + 3);
    }
    adjb[(size_t)row * NW32 + wd] = bits;
    return;
  }

  // ---- GEMM path ----
  const int r0 = bx * GROWS;
#pragma unroll
  for (int idx = t; idx < GROWS * FIN / 4; idx += 256) {
    const int r = idx >> 6, c4 = idx & 63;
    *(float4*)&hs[r][c4 * 4] =
        *(const float4*)&h[(size_t)(r0 + r) * FIN + c4 * 4];
  }
  __syncthreads();
  const int c = t;
  float acc[GROWS];
#pragma unroll
  for (int r = 0; r < GROWS; ++r) acc[r] = 0.f;
  for (int k = 0; k < FIN; k += 4) {
    const float w0 = W[(size_t)(k + 0) * CC + c];
    const float w1 = W[(size_t)(k + 1) * CC + c];
    const float w2 = W[(size_t)(k + 2) * CC + c];
    const float w3 = W[(size_t)(k + 3) * CC + c];
#pragma unroll
    for (int r = 0; r < GROWS; ++r) {
      const float4 hv = *(const float4*)&hs[r][k];
      acc[r] += hv.x * w0 + hv.y * w1 + hv.z * w2 + hv.w * w3;
    }
  }
  const int f = c & 31, hh = c >> 5;
  const float aS = a[f], aD = a[32 + f];
  unsigned short gu[GROWS];
#pragma unroll
  for (int r = 0; r < GROWS; ++r) {
    float ps = acc[r] * aS, pd = acc[r] * aD;
#pragma unroll
    for (int m = 1; m < 32; m <<= 1) {
      ps += __shfl_xor(ps, m, 64);
      pd += __shfl_xor(pd, m, 64);
    }
    if (f == 0) {
      const int n = r0 + r;
      spack[(size_t)hh * NN + n] =
          make_float4(__expf(ps), __expf(0.2f * ps), 0.f, 0.f);
      float* dc = dtc + ((size_t)hh * (NN / 32) + (n >> 5)) * 64 + (n & 31);
      dc[0] = __expf(pd);
      dc[32] = __expf(0.2f * pd);
    }
    gu[r] = bf16rn(acc[r]);
  }
  uint4 gv;
  gv.x = (unsigned)gu[0] | ((unsigned)gu[1] << 16);
  gv.y = (unsigned)gu[2] | ((unsigned)gu[3] << 16);
  gv.z = (unsigned)gu[4] | ((unsigned)gu[5] << 16);
  gv.w = (unsigned)gu[6] | ((unsigned)gu[7] << 16);
  const int jc = r0 >> 5, qq = (r0 >> 3) & 3;
  const int p = qq ^ ((c >> 1) & 3);
  *(uint4*)(gTs + ((size_t)jc * 1024 + c * 4 + p) * 8) = gv;
}

// ---------------- K2: in-block j-split, counted-vmcnt pipeline, tree-reduce
// Block = 32 i x 1 head x FULL 4096 j. 4 waves, wave w owns j-quarter in 16
// rounds of 64 j. Buffers are WAVE-PRIVATE -> NO barrier in the j-loop.
// gl_lds -> ds_read fencing via counted s_waitcnt vmcnt(14): each round
// issues exactly 14 VMEM ops (4 gl_lds + 8 dt float4 + 2 adj u64); two
// rounds stay in flight, so vmcnt(14) completes round r while r+1 streams.
// ONE __syncthreads after the loop; epilogue tree-reduce aliases gt_lds.
// NOTE: do not raise launch_bounds min-waves (R4/R11/R17 spill lesson).
// e^leaky(ss+sd) = max(e^ss*e^sd, e^{0.2ss}*e^{0.2sd})  (exact identity).
__global__ __launch_bounds__(256, 3) void k_attn(
    const unsigned int* __restrict__ adjb, const unsigned short* __restrict__ gTs,
    const float4* __restrict__ spack, const float* __restrict__ dtc,
    float* __restrict__ out) {
  __shared__ unsigned short gt_lds[4][2][2048];  // 32 KB: per-wave dbuf 4KB
  auto red = (float(*)[2][3][4][64]) & gt_lds[0][0][0];  // epilogue alias

  const int lane = threadIdx.x & 63;
  const int w = threadIdx.x >> 6;
  const int il = lane & 15, q = lane >> 4;
  const int bx = blockIdx.x;
  const int hh = bx & 7;   // head -> XCD-pinned via %8 round-robin
  const int ib = bx >> 3;
  const int i0 = ib * 32;

  // hoisted i-side scalars
  float e1v[2], e2v[2];
#pragma unroll
  for (int it = 0; it < 2; ++it) {
    const float4 v = spack[(size_t)hh * NN + i0 + it * 16 + il];
    e1v[it] = v.x; e2v[it] = v.y;
  }

  f32x4 acc[2][2];
  f32x4 lac[2];
#pragma unroll
  for (int it = 0; it < 2; ++it) {
#pragma unroll
    for (int r = 0; r < 4; ++r) lac[it][r] = 0.f;
#pragma unroll
    for (int ft = 0; ft < 2; ++ft)
#pragma unroll
      for (int r = 0; r < 4; ++r) acc[it][ft][r] = 0.f;
  }

  const short8 ones = {(short)0x3F80, (short)0x3F80, (short)0x3F80,
                       (short)0x3F80, (short)0x3F80, (short)0x3F80,
                       (short)0x3F80, (short)0x3F80};

  const unsigned long long* abr0 =
      (const unsigned long long*)(adjb + (size_t)(i0 + il) * NW32) + w * 16;
  const unsigned long long* abr1 =
      (const unsigned long long*)(adjb + (size_t)(i0 + 16 + il) * NW32) +
      w * 16;
  const float* dbase = dtc + ((size_t)hh * (NN / 32) + w * 32) * 64;
  const int sh = q * 8;
  const int u0 = il * 4 + (q ^ ((il >> 1) & 3));  // swizzled B-frag unit

  // stage one 64-j round: exactly 4 gl_lds (VMEM ops 1-4 of the round's 14)
  auto stage = [&](int buf, int rr) {
    const unsigned short* src =
        gTs + (((size_t)(w * 32 + rr * 2)) * 1024 + hh * 128) * 8;
    char* dst = (char*)&gt_lds[w][buf][0];
    gl_lds16(src + (size_t)lane * 8, dst);
    gl_lds16(src + (size_t)(64 + lane) * 8, dst + 1024);
    gl_lds16(src + (size_t)(1024 + lane) * 8, dst + 2048);
    gl_lds16(src + (size_t)(1024 + 64 + lane) * 8, dst + 3072);
  };

  // A/B register prefetch sets (static names — rule #20)
  unsigned long long Ab0, Ab1, Bb0, Bb1;
  float4 Ad0, Ad1, Ad2, Ad3, Ad4, Ad5, Ad6, Ad7;
  float4 Bd0, Bd1, Bd2, Bd3, Bd4, Bd5, Bd6, Bd7;

// 10 VMEM ops (8 x dwordx4 + 2 x dwordx2) — ops 5-14 of the round's 14
#define ISSUE_REGS(P, rr)                                  \
  {                                                        \
    P##b0 = abr0[rr]; P##b1 = abr1[rr];                    \
    const float* dp_ = dbase + (size_t)(rr) * 128;         \
    P##d0 = *(const float4*)(dp_ + q * 8);                 \
    P##d1 = *(const float4*)(dp_ + q * 8 + 4);             \
    P##d2 = *(const float4*)(dp_ + 32 + q * 8);            \
    P##d3 = *(const float4*)(dp_ + 32 + q * 8 + 4);        \
    P##d4 = *(const float4*)(dp_ + 64 + q * 8);            \
    P##d5 = *(const float4*)(dp_ + 64 + q * 8 + 4);        \
    P##d6 = *(const float4*)(dp_ + 96 + q * 8);            \
    P##d7 = *(const float4*)(dp_ + 96 + q * 8 + 4);        \
  }

// counted waits: memory-clobbered asm orders ALL memory ops (gl_lds,
// global loads, ds_read) across it — no sched_barrier order-pinning needed
#define WAIT14 asm volatile("s_waitcnt vmcnt(14)" ::: "memory")
#define WAIT0 asm volatile("s_waitcnt vmcnt(0)" ::: "memory")

#define COMPUTE(P, BUF)                                                     \
  {                                                                         \
    _Pragma("unroll") for (int sub = 0; sub < 2; ++sub) {                   \
      const unsigned int bits0 = (unsigned int)(P##b0 >> (sub * 32));       \
      const unsigned int bits1 = (unsigned int)(P##b1 >> (sub * 32));       \
      float e1j[8], e2j[8];                                                 \
      if (sub == 0) {                                                       \
        *(float4*)&e1j[0] = P##d0; *(float4*)&e1j[4] = P##d1;               \
        *(float4*)&e2j[0] = P##d2; *(float4*)&e2j[4] = P##d3;               \
      } else {                                                              \
        *(float4*)&e1j[0] = P##d4; *(float4*)&e1j[4] = P##d5;               \
        *(float4*)&e2j[0] = P##d6; *(float4*)&e2j[4] = P##d7;               \
      }                                                                     \
      const unsigned short* gb = &gt_lds[w][BUF][sub * 1024];               \
      const short8 b0 = *(const short8*)&gb[u0 * 8];                        \
      const short8 b1 = *(const short8*)&gb[(u0 + 64) * 8];                 \
      _Pragma("unroll") for (int it = 0; it < 2; ++it) {                    \
        const unsigned int bits = it ? bits1 : bits0;                       \
        const float ei1 = e1v[it], ei2 = e2v[it];                           \
        float wv[8];                                                        \
        _Pragma("unroll") for (int e = 0; e < 8; ++e)                       \
            wv[e] = ((bits >> (sh + e)) & 1u)                               \
                        ? fmaxf(ei1 * e1j[e], ei2 * e2j[e])                 \
                        : 0.f;                                              \
        u32x4 uu;                                                           \
        _Pragma("unroll") for (int m = 0; m < 4; ++m)                       \
            uu[m] = cvtpk_bf16(wv[2 * m], wv[2 * m + 1]);                   \
        const short8 afr = __builtin_bit_cast(short8, uu);                  \
        acc[it][0] = __builtin_amdgcn_mfma_f32_16x16x32_bf16(               \
            afr, b0, acc[it][0], 0, 0, 0);                                  \
        acc[it][1] = __builtin_amdgcn_mfma_f32_16x16x32_bf16(               \
            afr, b1, acc[it][1], 0, 0, 0);                                  \
        lac[it] = __builtin_amdgcn_mfma_f32_16x16x32_bf16(                  \
            afr, ones, lac[it], 0, 0, 0);                                   \
      }                                                                     \
    }                                                                       \
  }

  // prologue: rounds 0 and 1 fully issued (28 VMEM ops in flight)
  stage(0, 0);
  ISSUE_REGS(A, 0);
  stage(1, 1);
  ISSUE_REGS(B, 1);

#pragma unroll 1
  for (int r2 = 0; r2 < 7; ++r2) {
    const int r = r2 * 2;
    WAIT14;                 // round r's 14 ops done; round r+1's in flight
    COMPUTE(A, 0);
    stage(0, r + 2);
    ISSUE_REGS(A, r + 2);
    WAIT14;                 // round r+1 done; round r+2 in flight
    COMPUTE(B, 1);
    stage(1, r + 3);
    ISSUE_REGS(B, r + 3);
  }
  WAIT14;  // round 14 done; round 15 in flight
  COMPUTE(A, 0);
  WAIT0;   // round 15 done
  COMPUTE(B, 1);
#undef ISSUE_REGS
#undef COMPUTE
#undef WAIT14
#undef WAIT0

  __syncthreads();  // all waves' j-loop reads done before red aliases gt_lds

  // ---- cross-wave tree reduction (j-quarters -> full j sum) ----
  if (w >= 2) {
    const int s = w - 2;
#pragma unroll
    for (int it = 0; it < 2; ++it)
#pragma unroll
      for (int r = 0; r < 4; ++r) {
        red[s][it][0][r][lane] = acc[it][0][r];
        red[s][it][1][r][lane] = acc[it][1][r];
        red[s][it][2][r][lane] = lac[it][r];
      }
  }
  __syncthreads();
  if (w < 2) {
#pragma unroll
    for (int it = 0; it < 2; ++it)
#pragma unroll
      for (int r = 0; r < 4; ++r) {
        acc[it][0][r] += red[w][it][0][r][lane];
        acc[it][1][r] += red[w][it][1][r][lane];
        lac[it][r] += red[w][it][2][r][lane];
      }
  }
  __syncthreads();
  if (w == 1) {
#pragma unroll
    for (int it = 0; it < 2; ++it)
#pragma unroll
      for (int r = 0; r < 4; ++r) {
        red[0][it][0][r][lane] = acc[it][0][r];
        red[0][it][1][r][lane] = acc[it][1][r];
        red[0][it][2][r][lane] = lac[it][r];
      }
  }
  __syncthreads();
  if (w == 0) {
#pragma unroll
    for (int it = 0; it < 2; ++it)
#pragma unroll
      for (int r = 0; r < 4; ++r) {
        const float a0 = acc[it][0][r] + red[0][it][0][r][lane];
        const float a1 = acc[it][1][r] + red[0][it][1][r][lane];
        const float lsum = lac[it][r] + red[0][it][2][r][lane];
        const float inv = 1.f / lsum;
        const size_t irow = i0 + it * 16 + q * 4 + r;
        out[irow * CC + hh * 32 + il] = a0 * inv;
        out[irow * CC + hh * 32 + 16 + il] = a1 * inv;
      }
  }
}

extern "C" void kernel_launch(void* const* d_in, const int* in_sizes, int n_in,
                              void* d_out, int out_size, void* d_ws,
                              size_t ws_size, hipStream_t stream) {
  (void)in_sizes; (void)n_in; (void)out_size; (void)ws_size;
  const float* h = (const float*)d_in[0];
  const int* adj = (const int*)d_in[1];
  const float* W = (const float*)d_in[2];
  const float* a = (const float*)d_in[3];
  float* out = (float*)d_out;
  char* ws = (char*)d_ws;

  unsigned short* gTs = (unsigned short*)ws;               // 2 MB (swizzled)
  float4* spack = (float4*)(ws + (size_t)NN * CC * 2);     // 512 KB
  float* dtc = (float*)(spack + (size_t)NH * NN);          // 256 KB
  unsigned int* adjb =
      (unsigned int*)(dtc + (size_t)NH * (NN / 32) * 64);  // 2 MB

  k_gemm<<<GEMM_BLKS + BP_BLKS, 256, 0, stream>>>(h, W, a, adj, adjb, gTs,
                                                  spack, dtc);
  k_attn<<<(NN / 32) * NH, 256, 0, stream>>>(adjb, gTs, spack, dtc, out);
}

// Round 20
// 68.173 us; speedup vs baseline: 2.8251x; 2.8251x over previous
//
#include <hip/hip_runtime.h>

#define NN 4096
#define FIN 256
#define CC 256
#define NH 8
#define NW32 (NN / 32)  // u32 words per adj row

typedef __attribute__((ext_vector_type(8))) short short8;
typedef __attribute__((ext_vector_type(4))) float f32x4;
typedef __attribute__((ext_vector_type(4))) unsigned int u32x4;

__device__ __forceinline__ unsigned cvtpk_bf16(float lo, float hi) {
  unsigned r;
  asm("v_cvt_pk_bf16_f32 %0, %1, %2" : "=v"(r) : "v"(lo), "v"(hi));
  return r;
}

__device__ __forceinline__ unsigned short bf16rn(float x) {
  unsigned int u = __builtin_bit_cast(unsigned int, x);
  u += 0x7fffu + ((u >> 16) & 1u);
  return (unsigned short)(u >> 16);
}

__device__ __forceinline__ void gl_lds16(const void* g, void* l) {
  __builtin_amdgcn_global_load_lds(
      (const __attribute__((address_space(1))) void*)g,
      (__attribute__((address_space(3))) void*)l, 16, 0, 0);
}

// ---------------- K1: fused {GEMM+epilogue | adj bitpack} by block range ---
// blocks [0,512): GEMM g=h@W -> swizzled gTs + spack + dtc.
// blocks [512, 512+2048): bitpack (one u32 word per thread, 8x int4 stream).
// adjb[i][w] bit e = adj[i][w*32+e]!=0.
// gTs: chunk-major SWIZZLED bf16 (16B unit at [jc][c][p], p = q ^ ((c>>1)&3)).
// spack[h][n] = (e^s_src, e^{0.2 s_src}, 0, 0).
// dtc[jc][h][plane][32] = (e^sd, e^{0.2 sd})  (head-sliceable).
#define GROWS 8
#define GEMM_BLKS (NN / GROWS)                  // 512
#define BP_BLKS (NN * NW32 / 256)               // 2048
__global__ __launch_bounds__(256) void k_gemm(
    const float* __restrict__ h, const float* __restrict__ W,
    const float* __restrict__ a, const int* __restrict__ adj,
    unsigned int* __restrict__ adjb, unsigned short* __restrict__ gTs,
    float4* __restrict__ spack, float* __restrict__ dtc) {
  __shared__ float hs[GROWS][FIN];
  const int t = threadIdx.x;
  const int bx = blockIdx.x;

  if (bx >= GEMM_BLKS) {
    const int wid = (bx - GEMM_BLKS) * 256 + t;  // word index
    const int row = wid >> 7, wd = wid & 127;
    const int* src = adj + (size_t)row * NN + wd * 32;
    int4 v[8];
#pragma unroll
    for (int s = 0; s < 8; ++s) v[s] = *(const int4*)&src[s * 4];
    unsigned int bits = 0;
#pragma unroll
    for (int s = 0; s < 8; ++s) {
      bits |= (v[s].x ? 1u : 0u) << (s * 4 + 0);
      bits |= (v[s].y ? 1u : 0u) << (s * 4 + 1);
      bits |= (v[s].z ? 1u : 0u) << (s * 4 + 2);
      bits |= (v[s].w ? 1u : 0u) << (s * 4 + 3);
    }
    adjb[(size_t)row * NW32 + wd] = bits;
    return;
  }

  // ---- GEMM path ----
  const int r0 = bx * GROWS;
#pragma unroll
  for (int idx = t; idx < GROWS * FIN / 4; idx += 256) {
    const int r = idx >> 6, c4 = idx & 63;
    *(float4*)&hs[r][c4 * 4] =
        *(const float4*)&h[(size_t)(r0 + r) * FIN + c4 * 4];
  }
  __syncthreads();
  const int c = t;
  float acc[GROWS];
#pragma unroll
  for (int r = 0; r < GROWS; ++r) acc[r] = 0.f;
  for (int k = 0; k < FIN; k += 4) {
    const float w0 = W[(size_t)(k + 0) * CC + c];
    const float w1 = W[(size_t)(k + 1) * CC + c];
    const float w2 = W[(size_t)(k + 2) * CC + c];
    const float w3 = W[(size_t)(k + 3) * CC + c];
#pragma unroll
    for (int r = 0; r < GROWS; ++r) {
      const float4 hv = *(const float4*)&hs[r][k];
      acc[r] += hv.x * w0 + hv.y * w1 + hv.z * w2 + hv.w * w3;
    }
  }
  const int f = c & 31, hh = c >> 5;
  const float aS = a[f], aD = a[32 + f];
  unsigned short gu[GROWS];
#pragma unroll
  for (int r = 0; r < GROWS; ++r) {
    float ps = acc[r] * aS, pd = acc[r] * aD;
#pragma unroll
    for (int m = 1; m < 32; m <<= 1) {
      ps += __shfl_xor(ps, m, 64);
      pd += __shfl_xor(pd, m, 64);
    }
    if (f == 0) {
      const int n = r0 + r;
      spack[(size_t)hh * NN + n] =
          make_float4(__expf(ps), __expf(0.2f * ps), 0.f, 0.f);
      float* dc = dtc + ((size_t)(n >> 5) * NH + hh) * 64 + (n & 31);
      dc[0] = __expf(pd);
      dc[32] = __expf(0.2f * pd);
    }
    gu[r] = bf16rn(acc[r]);
  }
  uint4 gv;
  gv.x = (unsigned)gu[0] | ((unsigned)gu[1] << 16);
  gv.y = (unsigned)gu[2] | ((unsigned)gu[3] << 16);
  gv.z = (unsigned)gu[4] | ((unsigned)gu[5] << 16);
  gv.w = (unsigned)gu[6] | ((unsigned)gu[7] << 16);
  const int jc = r0 >> 5, qq = (r0 >> 3) & 3;
  const int p = qq ^ ((c >> 1) & 3);
  *(uint4*)(gTs + ((size_t)jc * 1024 + c * 4 + p) * 8) = gv;
}

// ---------------- K2: LDS 2-phase (JB=128) fused masked-softmax + MFMA PV --
// Block = 128 i x 2 heads; 4 waves = 4 i-quarters sharing the head-pair ->
// staged gt read by ALL waves (4x reuse). Buffer = 128 j (4 subs of 32 j):
// gt 16KB + dt 2KB; double-buffered 36KB. 4 barriers per block (halved vs
// JB=64). No asm waits (R15/R19 lessons); barrier fences gl_lds -> ds_read.
// e^leaky(ss+sd) = max(e^ss*e^sd, e^{0.2ss}*e^{0.2sd})  (exact identity).
struct Buf {
  unsigned short gt[4][2048];  // 16 KB: [sub][unit u = relc*4 + (q^swz(relc))]
  float dt[4][2][2][32];       // 2 KB:  [sub][hrel][plane][j]
};

__global__ __launch_bounds__(256, 3) void k_attn(
    const unsigned int* __restrict__ adjb, const unsigned short* __restrict__ gTs,
    const float4* __restrict__ spack, const float* __restrict__ dtc,
    float* __restrict__ acc_ws, float* __restrict__ l_ws,
    float* __restrict__ out, const int splits, const int direct) {
  __shared__ Buf buf[2];  // 36 KB

  const int lane = threadIdx.x & 63;
  const int w = threadIdx.x >> 6;
  const int il = lane & 15, q = lane >> 4;
  const int bx = blockIdx.x;
  const int sp = bx & (splits - 1);
  const int rest = bx / splits;
  const int hg = rest & 3;                  // head-group: heads {2hg, 2hg+1}
  const int ib = rest >> 2;
  const int i0w = ib * 128 + w * 32;        // this wave's 32 i-rows
  const int jrange = NN / splits, j0b = sp * jrange;
  const int c0 = j0b >> 5;                  // first 32-chunk index

  // hoisted i-side scalars (2 heads x 2 it)
  float e1v[2][2], e2v[2][2];
#pragma unroll
  for (int hp = 0; hp < 2; ++hp)
#pragma unroll
    for (int it = 0; it < 2; ++it) {
      const float4 v = spack[(size_t)(hg * 2 + hp) * NN + i0w + it * 16 + il];
      e1v[hp][it] = v.x; e2v[hp][it] = v.y;
    }

  f32x4 acc[2][2][2];
  f32x4 lac[2][2];
#pragma unroll
  for (int hp = 0; hp < 2; ++hp)
#pragma unroll
    for (int it = 0; it < 2; ++it) {
#pragma unroll
      for (int r = 0; r < 4; ++r) lac[hp][it][r] = 0.f;
#pragma unroll
      for (int ft = 0; ft < 2; ++ft)
#pragma unroll
        for (int r = 0; r < 4; ++r) acc[hp][it][ft][r] = 0.f;
    }

  const short8 ones = {(short)0x3F80, (short)0x3F80, (short)0x3F80,
                       (short)0x3F80, (short)0x3F80, (short)0x3F80,
                       (short)0x3F80, (short)0x3F80};

  // bitpacked adj: 2 u64 per row per 128-j buffer
  const unsigned long long* ab0 =
      (const unsigned long long*)(adjb + (size_t)(i0w + il) * NW32) +
      (j0b >> 6);
  const unsigned long long* ab1 =
      (const unsigned long long*)(adjb + (size_t)(i0w + 16 + il) * NW32) +
      (j0b >> 6);
  const int sh = q * 8;
  const int pswz = q ^ ((il >> 1) & 3);

  // ---- staging: linear gt slice (pre-swizzled) + dt head-slice ----
  auto stage = [&](Buf* b, int jb) {
#pragma unroll
    for (int sub = 0; sub < 4; ++sub) {
      const unsigned short* src =
          gTs + ((size_t)(c0 + jb * 4 + sub) * 1024 + hg * 256 + w * 64) * 8;
      gl_lds16(src + (size_t)lane * 8, (char*)&b->gt[sub][0] + (w * 64) * 16);
    }
    if (w < 2) {
      // unit u = w*64+lane in [0,128): sub=u>>5, v=u&31 -> hrel=v>>4,
      // plane=(v>>3)&1, j4=(v&7)*4
      const int u = w * 64 + lane;
      const int sub = u >> 5, v = u & 31;
      const float* dsrc =
          dtc +
          ((size_t)(c0 + jb * 4 + sub) * NH + hg * 2 + (v >> 4)) * 64 +
          ((v >> 3) & 1) * 32 + (v & 7) * 4;
      gl_lds16(dsrc, (char*)&b->dt[0][0][0][0] + (size_t)u * 16);
    }
  };

  const int nbuf = jrange / 128;
  stage(&buf[0], 0);
  unsigned long long p0a = ab0[0], p0b = ab0[1];
  unsigned long long p1a = ab1[0], p1b = ab1[1];
  __syncthreads();
  int cur = 0;

  for (int jb = 0; jb < nbuf; ++jb) {
    if (jb + 1 < nbuf) stage(&buf[cur ^ 1], jb + 1);
    const Buf* bc = &buf[cur];
    const unsigned int bl0[4] = {(unsigned int)p0a, (unsigned int)(p0a >> 32),
                                 (unsigned int)p0b, (unsigned int)(p0b >> 32)};
    const unsigned int bl1[4] = {(unsigned int)p1a, (unsigned int)(p1a >> 32),
                                 (unsigned int)p1b, (unsigned int)(p1b >> 32)};
    if (jb + 1 < nbuf) {
      p0a = ab0[(jb + 1) * 2]; p0b = ab0[(jb + 1) * 2 + 1];
      p1a = ab1[(jb + 1) * 2]; p1b = ab1[(jb + 1) * 2 + 1];
    }

#pragma unroll
    for (int sub = 0; sub < 4; ++sub) {
      float adf[2][8];
#pragma unroll
      for (int e = 0; e < 8; ++e) {
        adf[0][e] = (float)((bl0[sub] >> (sh + e)) & 1u);
        adf[1][e] = (float)((bl1[sub] >> (sh + e)) & 1u);
      }
#pragma unroll
      for (int hp = 0; hp < 2; ++hp) {
        float e1j[8], e2j[8];
        *(float4*)&e1j[0] = *(const float4*)&bc->dt[sub][hp][0][q * 8];
        *(float4*)&e1j[4] = *(const float4*)&bc->dt[sub][hp][0][q * 8 + 4];
        *(float4*)&e2j[0] = *(const float4*)&bc->dt[sub][hp][1][q * 8];
        *(float4*)&e2j[4] = *(const float4*)&bc->dt[sub][hp][1][q * 8 + 4];
        const int u0 = (hp * 32 + il) * 4 + pswz;
        const short8 b0 = *(const short8*)&bc->gt[sub][u0 * 8];
        const short8 b1 = *(const short8*)&bc->gt[sub][(u0 + 64) * 8];
#pragma unroll
        for (int it = 0; it < 2; ++it) {
          const float ei1 = e1v[hp][it], ei2 = e2v[hp][it];
          float wv[8];
#pragma unroll
          for (int e = 0; e < 8; ++e)
            wv[e] = fmaxf(ei1 * e1j[e], ei2 * e2j[e]) * adf[it][e];
          u32x4 uu;
#pragma unroll
          for (int m = 0; m < 4; ++m)
            uu[m] = cvtpk_bf16(wv[2 * m], wv[2 * m + 1]);
          const short8 afr = __builtin_bit_cast(short8, uu);
          acc[hp][it][0] = __builtin_amdgcn_mfma_f32_16x16x32_bf16(
              afr, b0, acc[hp][it][0], 0, 0, 0);
          acc[hp][it][1] = __builtin_amdgcn_mfma_f32_16x16x32_bf16(
              afr, b1, acc[hp][it][1], 0, 0, 0);
          lac[hp][it] = __builtin_amdgcn_mfma_f32_16x16x32_bf16(
              afr, ones, lac[hp][it], 0, 0, 0);
        }
      }
    }
    __syncthreads();  // drains staging vmcnt + read lgkm; swap safe
    cur ^= 1;
  }

  if (direct) {
#pragma unroll
    for (int hp = 0; hp < 2; ++hp) {
      const int hh = hg * 2 + hp;
#pragma unroll
      for (int it = 0; it < 2; ++it)
#pragma unroll
        for (int r = 0; r < 4; ++r) {
          const float inv = 1.f / lac[hp][it][r];
          const size_t irow = i0w + it * 16 + q * 4 + r;
#pragma unroll
          for (int ft = 0; ft < 2; ++ft)
            out[irow * CC + hh * 32 + ft * 16 + il] =
                acc[hp][it][ft][r] * inv;
        }
    }
  } else {
#pragma unroll
    for (int hp = 0; hp < 2; ++hp) {
      const int hh = hg * 2 + hp;
#pragma unroll
      for (int it = 0; it < 2; ++it)
#pragma unroll
        for (int r = 0; r < 4; ++r) {
          const size_t irow = i0w + it * 16 + q * 4 + r;
          if (il == 0)
            l_ws[((size_t)sp * NH + hh) * NN + irow] = lac[hp][it][r];
#pragma unroll
          for (int ft = 0; ft < 2; ++ft)
            acc_ws[((size_t)sp * NN + irow) * CC + hh * 32 + ft * 16 + il] =
                acc[hp][it][ft][r];
        }
    }
  }
}

// ---------------- K3: combine split partials ----------------
__global__ __launch_bounds__(256) void k_combine(
    const float* __restrict__ acc_ws, const float* __restrict__ l_ws,
    float* __restrict__ out, const int splits) {
  const int idx = blockIdx.x * 256 + threadIdx.x;  // float4 index
  const int row = idx >> 6, c4 = idx & 63;
  const int hh = c4 >> 3;
  float ax = 0.f, ay = 0.f, az = 0.f, aw = 0.f, l = 0.f;
  for (int s = 0; s < splits; ++s) {
    const float4 v =
        *(const float4*)&acc_ws[((size_t)s * NN + row) * CC + c4 * 4];
    ax += v.x; ay += v.y; az += v.z; aw += v.w;
    l += l_ws[((size_t)s * NH + hh) * NN + row];
  }
  const float inv = 1.f / l;
  *(float4*)&out[(size_t)row * CC + c4 * 4] =
      make_float4(ax * inv, ay * inv, az * inv, aw * inv);
}

extern "C" void kernel_launch(void* const* d_in, const int* in_sizes, int n_in,
                              void* d_out, int out_size, void* d_ws,
                              size_t ws_size, hipStream_t stream) {
  (void)in_sizes; (void)n_in; (void)out_size;
  const float* h = (const float*)d_in[0];
  const int* adj = (const int*)d_in[1];
  const float* W = (const float*)d_in[2];
  const float* a = (const float*)d_in[3];
  float* out = (float*)d_out;
  char* ws = (char*)d_ws;

  unsigned short* gTs = (unsigned short*)ws;               // 2 MB (swizzled)
  float4* spack = (float4*)(ws + (size_t)NN * CC * 2);     // 512 KB
  float* dtc = (float*)(spack + (size_t)NH * NN);          // 256 KB
  unsigned int* adjb =
      (unsigned int*)(dtc + (size_t)(NN / 32) * NH * 64);  // 2 MB
  char* after = (char*)(adjb + (size_t)NN * NW32);
  const size_t base = (size_t)(after - ws);
  const size_t per_split = (size_t)NN * CC * 4 + (size_t)NH * NN * 4;

  int splits = 1;
  if (ws_size >= base + 8 * per_split) splits = 8;
  else if (ws_size >= base + 4 * per_split) splits = 4;
  else if (ws_size >= base + 2 * per_split) splits = 2;

  k_gemm<<<GEMM_BLKS + BP_BLKS, 256, 0, stream>>>(h, W, a, adj, adjb, gTs,
                                                  spack, dtc);

  const int nblk = (NN / 128) * 4 * splits;
  if (splits == 1) {
    k_attn<<<nblk, 256, 0, stream>>>(adjb, gTs, spack, dtc, nullptr, nullptr,
                                     out, 1, 1);
  } else {
    float* acc_ws = (float*)after;
    float* l_ws = acc_ws + (size_t)splits * NN * CC;
    k_attn<<<nblk, 256, 0, stream>>>(adjb, gTs, spack, dtc, acc_ws, l_ws, out,
                                     splits, 0);
    k_combine<<<NN * CC / 4 / 256, 256, 0, stream>>>(acc_ws, l_ws, out,
                                                     splits);
  }
}